// Round 13
// baseline (211.687 us; speedup 1.0000x reference)
//
#include <hip/hip_runtime.h>
#include <stdint.h>

#define SEQ 2048
#define NH  16
#define DK  64
#define DM  1024
#define C2SM 0.18033688011112042f   // 0.125 * log2(e): folds 1/sqrt(64) into exp2

typedef __bf16 bf16x8 __attribute__((ext_vector_type(8)));
typedef float  f32x4  __attribute__((ext_vector_type(4)));
typedef float  f32x16 __attribute__((ext_vector_type(16)));
typedef int    iv2    __attribute__((ext_vector_type(2)));
typedef void __attribute__((address_space(3))) lds_void;
typedef const void __attribute__((address_space(1))) glb_void;

__device__ __forceinline__ unsigned short f2b(float f) {
  unsigned int u = __float_as_uint(f);
  u += 0x7fffu + ((u >> 16) & 1u);
  return (unsigned short)(u >> 16);
}
__device__ __forceinline__ float b2f(unsigned short h) {
  return __uint_as_float(((unsigned int)h) << 16);
}
__device__ __forceinline__ void gload_lds16(const void* g, void* lds) {
  __builtin_amdgcn_global_load_lds((glb_void*)(uintptr_t)g,
                                   (lds_void*)(unsigned int)(uintptr_t)lds,
                                   16, 0, 0);
}
// pack two f32 -> one u32 of two bf16 (RNE), single VALU op (no builtin, m240)
__device__ __forceinline__ unsigned int cvtpk(float lo, float hi) {
  unsigned int r;
  asm("v_cvt_pk_bf16_f32 %0, %1, %2" : "=v"(r) : "v"(lo), "v"(hi));
  return r;
}
__device__ __forceinline__ iv2 pl32swap(int a, int b) {
  return __builtin_amdgcn_permlane32_swap(a, b, false, false);
}

// ---------------- f32 -> bf16 convert (x) ----------------
__global__ __launch_bounds__(256) void k_cvt(const float* __restrict__ src,
                                             unsigned short* __restrict__ dst, int n4) {
  int i = blockIdx.x * 256 + threadIdx.x;
  if (i >= n4) return;
  float4 v = ((const float4*)src)[i];
  uint2 o;
  o.x = (unsigned int)f2b(v.x) | ((unsigned int)f2b(v.y) << 16);
  o.y = (unsigned int)f2b(v.z) | ((unsigned int)f2b(v.w) << 16);
  ((uint2*)dst)[i] = o;
}

// ---------------- all 4 weights -> contiguous bf16 ----------------
__global__ __launch_bounds__(256) void k_cvtw(const float* __restrict__ w0,
                                              const float* __restrict__ w1,
                                              const float* __restrict__ w2,
                                              const float* __restrict__ w3,
                                              unsigned short* __restrict__ dst) {
  int i = blockIdx.x * 256 + threadIdx.x;   // 0..2^20-1 (float4 units)
  const float* s = (i < 524288) ? ((i < 262144) ? w0 : w1)
                                : ((i < 786432) ? w2 : w3);
  float4 v = ((const float4*)s)[i & 262143];
  uint2 o;
  o.x = (unsigned int)f2b(v.x) | ((unsigned int)f2b(v.y) << 16);
  o.y = (unsigned int)f2b(v.z) | ((unsigned int)f2b(v.w) << 16);
  ((uint2*)dst)[i] = o;
}

// ---------------- RoPE cos/sin table: [SEQ][32] ----------------
__global__ __launch_bounds__(256) void k_tab(float2* __restrict__ tab) {
  int i = blockIdx.x * 256 + threadIdx.x;
  int p = i >> 5, f = i & 31;
  float freq = powf(10000.0f, -(float)(2 * f) / (float)DK);
  float ang = (float)p * freq;
  tab[i] = make_float2(cosf(ang), sinf(ang));
}

// ---------------- GEMM: C = A[M][K] * B[N][K]^T (bf16 in) ----------------
// R8-proven config: 128x128 tile, depth-2 pipeline (3 LDS buffers), counted
// vmcnt(4), T2 slot swizzle (pre-swizzled source + same XOR on reads).
// MODE 1: f32 out, row-major [M][N]                        (final projection)
// MODE 3: fused QKV. N=3072 (Wq;Wk;Wv). Q/K cols: RoPE applied in-register
//         (pair partner via shfl_xor lane^1), bf16 out to [B][NH][SEQ][DK]
//         (Q at C, K at C+8M). V cols: bf16 out to C2 as V^T [B][NH][DK][SEQ]
//         directly (packed uint2: 4 consecutive s per thread) — k_vt deleted.
template <int MODE>
__global__ __launch_bounds__(256) void k_gemm(const unsigned short* __restrict__ A,
                                              const unsigned short* __restrict__ B,
                                              void* __restrict__ C, void* __restrict__ C2,
                                              const int* __restrict__ pos,
                                              const float2* __restrict__ tab,
                                              int M, int N, int K) {
  __shared__ __align__(16) unsigned short As[3][4096];
  __shared__ __align__(16) unsigned short Bs[3][4096];
  const int tid = threadIdx.x;
  const int wid = tid >> 6, lane = tid & 63;
  const int lr = lane & 15, lk = lane >> 4;
  const int wr = wid >> 1, wc = wid & 1;
  const int m0 = blockIdx.x * 128, n0 = blockIdx.y * 128;
  const int r0 = tid >> 2;                                  // staging row (rep0)
  const int csw = (((tid & 3) ^ ((r0 >> 1) & 3)) << 3);     // pre-swizzled src col
  const int ss = ((lk ^ ((lr >> 1) & 3)) << 3);             // swizzled read slot
  f32x4 acc[4][4] = {};

#define GSTAGE(bi, k0)                                                       \
  do {                                                                       \
    gload_lds16(A + (size_t)(m0 + r0) * K + (k0) + csw, &As[bi][wid * 512]); \
    gload_lds16(A + (size_t)(m0 + 64 + r0) * K + (k0) + csw,                 \
                &As[bi][2048 + wid * 512]);                                  \
    gload_lds16(B + (size_t)(n0 + r0) * K + (k0) + csw, &Bs[bi][wid * 512]); \
    gload_lds16(B + (size_t)(n0 + 64 + r0) * K + (k0) + csw,                 \
                &Bs[bi][2048 + wid * 512]);                                  \
  } while (0)

  const int nt = K >> 5;
  GSTAGE(0, 0);
  if (nt > 1) {
    GSTAGE(1, 32);
    asm volatile("s_waitcnt vmcnt(4)" ::: "memory");   // buf0 landed, buf1 flying
  } else {
    asm volatile("s_waitcnt vmcnt(0)" ::: "memory");
  }
  __builtin_amdgcn_s_barrier();
  int c0 = 0, c1 = 1, c2 = 2;
  for (int t = 0; t < nt; ++t) {
    if (t + 2 < nt) GSTAGE(c2, (t + 2) * 32);          // overwrites buf read at t-1
    bf16x8 af[4], bfv[4];
#pragma unroll
    for (int i = 0; i < 4; ++i)
      af[i] = *(const bf16x8*)&As[c0][(wr * 64 + i * 16 + lr) * 32 + ss];
#pragma unroll
    for (int j = 0; j < 4; ++j)
      bfv[j] = *(const bf16x8*)&Bs[c0][(wc * 64 + j * 16 + lr) * 32 + ss];
    __builtin_amdgcn_s_setprio(1);
#pragma unroll
    for (int i = 0; i < 4; ++i)
#pragma unroll
      for (int j = 0; j < 4; ++j)
        acc[i][j] = __builtin_amdgcn_mfma_f32_16x16x32_bf16(af[i], bfv[j], acc[i][j], 0, 0, 0);
    __builtin_amdgcn_s_setprio(0);
    if (t + 1 < nt) {
      if (t + 2 < nt)
        asm volatile("s_waitcnt vmcnt(4)" ::: "memory");  // t+1 landed, t+2 flying
      else
        asm volatile("s_waitcnt vmcnt(0)" ::: "memory");
      __builtin_amdgcn_s_barrier();                       // + buf c0 consumed by all
    }
    int tmp = c0; c0 = c1; c1 = c2; c2 = tmp;
  }
#undef GSTAGE

  if (MODE == 1) {
#pragma unroll
    for (int i = 0; i < 4; ++i) {
      const int rbase = m0 + wr * 64 + i * 16 + lk * 4;
#pragma unroll
      for (int j = 0; j < 4; ++j) {
        const int col = n0 + wc * 64 + j * 16 + lr;
#pragma unroll
        for (int r = 0; r < 4; ++r)
          ((float*)C)[(size_t)(rbase + r) * N + col] = acc[i][j][r];
      }
    }
  } else {
    const int tt = n0 >> 10;                  // 0=Q 1=K 2=V, uniform per block
    if (tt == 2) {
      // direct V^T: VT[((bb*NH+h)*DK+d)*SEQ + s], 4 consecutive s -> uint2
#pragma unroll
      for (int i = 0; i < 4; ++i) {
        const int rbase = m0 + wr * 64 + i * 16 + lk * 4;
        const int bb = rbase >> 11;
        const int s0 = rbase & (SEQ - 1);
#pragma unroll
        for (int j = 0; j < 4; ++j) {
          const int col = n0 + wc * 64 + j * 16 + lr;
          const int h = (col >> 6) & 15, d = col & 63;
          uint2 pv;
          pv.x = cvtpk(acc[i][j][0], acc[i][j][1]);
          pv.y = cvtpk(acc[i][j][2], acc[i][j][3]);
          *(uint2*)&((unsigned short*)C2)[(((size_t)bb * NH + h) * DK + d) * SEQ + s0] = pv;
        }
      }
    } else {
#pragma unroll
      for (int i = 0; i < 4; ++i) {
        const int rbase = m0 + wr * 64 + i * 16 + lk * 4;
        const int bb = rbase >> 11;
        int prr[4];
#pragma unroll
        for (int r = 0; r < 4; ++r)
          prr[r] = pos[bb * SEQ + ((rbase + r) & (SEQ - 1))];
#pragma unroll
        for (int j = 0; j < 4; ++j) {
          const int col = n0 + wc * 64 + j * 16 + lr;
          const int h = (col >> 6) & 15, d = col & 63;
          const int f = d >> 1;
#pragma unroll
          for (int r = 0; r < 4; ++r) {
            float v = acc[i][j][r];
            float pv = __shfl_xor(v, 1);
            float2 cs = tab[(size_t)prr[r] * 32 + f];
            float o = (d & 1) ? __builtin_fmaf(pv, cs.y, v * cs.x)
                              : __builtin_fmaf(-pv, cs.y, v * cs.x);
            const int s = (rbase + r) & (SEQ - 1);
            ((unsigned short*)C)[(size_t)tt * 8388608 +
                                 ((((size_t)bb * NH + h) * SEQ) + s) * DK + d] = f2b(o);
          }
        }
      }
    }
  }
}

// ---------------- causal flash attention: 3-buffer depth-2, ONE barrier/tile ----------------
// 1024 blocks x 128 threads (2 waves x 32 q-rows, QBLK=64). Fold-pairs over 32
// q-tiles (qt = x then 31-x -> exactly 33 K-tiles/block, uniform per BLOCK);
// bh-major index keeps K/V L2-resident (R9-verified). NEW: GEMM-style 3-buffer
// rotation — STAGE(t+2) at iter top, compute t, then ONE vmcnt(8) + ONE
// s_barrier per tile (was 2 barriers + 2 waits). Induction: end-of-t vmcnt(8)
// retires tile t+1's 8 loads (outstanding = t+1's + t+2's); the barrier also
// protects the WAR on buffer (t+2)%3 (last read at t-1). Depth-2 gives each
// tile's loads ~2 tiles of latency budget.
__global__ __launch_bounds__(128) void k_attn(const unsigned short* __restrict__ Q,
                                              const unsigned short* __restrict__ K,
                                              const unsigned short* __restrict__ VT,
                                              unsigned short* __restrict__ O) {
  __shared__ __align__(16) unsigned short Ks[3][64 * 64];
  __shared__ __align__(16) unsigned short Vs[3][64 * 64];
  const int tid = threadIdx.x, wid = tid >> 6, lane = tid & 63;
  const int l31 = lane & 31, hi = lane >> 5;
  const int n = blockIdx.x;
  const int bh = n & 63, x = n >> 6;           // bh-major: XCD = bh%8
  const unsigned short* Qp = Q + (size_t)bh * SEQ * DK;
  const unsigned short* Kp = K + (size_t)bh * SEQ * DK;
  const unsigned short* Vp = VT + (size_t)bh * DK * SEQ;   // [64 d][SEQ]
  const int b = bh >> 4, h = bh & (NH - 1);

#define STAGE(bi, kb)                                                          \
  do {                                                                         \
    _Pragma("unroll") for (int i = 0; i < 4; ++i) {                            \
      const int c = i * 128 + tid;                                             \
      const int row = c >> 3, sl = ((c & 7) ^ (row & 7)) << 3;                 \
      gload_lds16(Kp + (size_t)((kb) + row) * DK + sl,                         \
                  &Ks[bi][(i * 128 + wid * 64) * 8]);                          \
      gload_lds16(Vp + (size_t)row * SEQ + (kb) + sl,                          \
                  &Vs[bi][(i * 128 + wid * 64) * 8]);                          \
    }                                                                          \
  } while (0)

#pragma unroll
  for (int pass = 0; pass < 2; ++pass) {
    const int qt = pass ? 31 - x : x;
    const int qw = qt * 64 + wid * 32;
    const int qrow = qw + l31;
    bf16x8 qf[4];
#pragma unroll
    for (int ks = 0; ks < 4; ++ks)
      qf[ks] = *(const bf16x8*)&Qp[(size_t)qrow * DK + ks * 16 + hi * 8];
    f32x16 oacc[2] = {};
    float m_ = -1e30f, l_ = 0.f;
    const int ntiles = qt + 1;
    int c0 = 0, c1 = 1, c2 = 2;
    STAGE(0, 0);                               // prologue depth-2 prefetch
    if (ntiles > 1) {
      STAGE(1, 64);
      asm volatile("s_waitcnt vmcnt(8)" ::: "memory");   // tile0 landed
    } else {
      asm volatile("s_waitcnt vmcnt(0)" ::: "memory");
    }
    __builtin_amdgcn_s_barrier();
    for (int kt = 0; kt < ntiles; ++kt) {
      const int kb = kt * 64;
      if (kt + 2 < ntiles) STAGE(c2, kb + 128);          // overwrites buf read at kt-1
      {
        // ---- QK^T (swapped): sa[kg] regs = kcols kg*32+(r&3)+8(r>>2)+4hi ----
        f32x16 sa[2];
        __builtin_amdgcn_s_setprio(1);
#pragma unroll
        for (int kg = 0; kg < 2; ++kg) {
          const int krow = kg * 32 + l31;
          f32x16 z = {};
#pragma unroll
          for (int ks = 0; ks < 4; ++ks) {
            bf16x8 kf = *(const bf16x8*)((const char*)&Ks[c0][0] + krow * 128 +
                                         (((2 * ks + hi) ^ (krow & 7)) << 4));
            z = __builtin_amdgcn_mfma_f32_32x32x16_bf16(kf, qf[ks], z, 0, 0, 0);
          }
          sa[kg] = z;
        }
        __builtin_amdgcn_s_setprio(0);
        // ---- causal mask (diagonal tile only) ----
        if (kb + 64 > qw) {
          const int th0 = qrow - kb - 4 * hi;
#pragma unroll
          for (int kg = 0; kg < 2; ++kg) {
            const int th = th0 - kg * 32;
#pragma unroll
            for (int r = 0; r < 16; ++r) {
              const int cst = (r & 3) + 8 * (r >> 2);
              if (cst > th) sa[kg][r] = -1e30f;
            }
          }
        }
        // ---- row max: in-register tree + lane-pair swap ----
        float mx;
        {
          float a0 = fmaxf(fmaxf(sa[0][0], sa[0][1]), fmaxf(sa[0][2], sa[0][3]));
          float a1 = fmaxf(fmaxf(sa[0][4], sa[0][5]), fmaxf(sa[0][6], sa[0][7]));
          float a2 = fmaxf(fmaxf(sa[0][8], sa[0][9]), fmaxf(sa[0][10], sa[0][11]));
          float a3 = fmaxf(fmaxf(sa[0][12], sa[0][13]), fmaxf(sa[0][14], sa[0][15]));
          float a4 = fmaxf(fmaxf(sa[1][0], sa[1][1]), fmaxf(sa[1][2], sa[1][3]));
          float a5 = fmaxf(fmaxf(sa[1][4], sa[1][5]), fmaxf(sa[1][6], sa[1][7]));
          float a6 = fmaxf(fmaxf(sa[1][8], sa[1][9]), fmaxf(sa[1][10], sa[1][11]));
          float a7 = fmaxf(fmaxf(sa[1][12], sa[1][13]), fmaxf(sa[1][14], sa[1][15]));
          mx = fmaxf(fmaxf(fmaxf(a0, a1), fmaxf(a2, a3)),
                     fmaxf(fmaxf(a4, a5), fmaxf(a6, a7)));
          iv2 t = pl32swap(__float_as_int(mx), __float_as_int(mx));
          mx = fmaxf(__int_as_float(t.x), __int_as_float(t.y));
        }
        // ---- defer-max: rescale only when running max moved by > 16 (raw) ----
        if (!__all(mx <= m_ + 16.f)) {
          const float mn = fmaxf(m_, mx);
          const float sc = __builtin_amdgcn_exp2f((m_ - mn) * C2SM);
          m_ = mn;
          l_ *= sc;
#pragma unroll
          for (int vg = 0; vg < 2; ++vg)
#pragma unroll
            for (int r = 0; r < 16; ++r) oacc[vg][r] *= sc;
        }
        // ---- exp + row sum ----
        const float mc = m_ * C2SM;
        float sum = 0.f;
#pragma unroll
        for (int kg = 0; kg < 2; ++kg)
#pragma unroll
          for (int r = 0; r < 16; ++r) {
            const float p = __builtin_amdgcn_exp2f(__builtin_fmaf(sa[kg][r], C2SM, -mc));
            sa[kg][r] = p;
            sum += p;
          }
        {
          iv2 t = pl32swap(__float_as_int(sum), __float_as_int(sum));
          l_ += __int_as_float(t.x) + __int_as_float(t.y);
        }
        // ---- PV: P->bf16 A-frag via cvt_pk + permlane32_swap, mfma(V^T, P) ----
        __builtin_amdgcn_s_setprio(1);
#pragma unroll
        for (int kg = 0; kg < 2; ++kg)
#pragma unroll
          for (int ks2 = 0; ks2 < 2; ++ks2) {
            const int rb = ks2 * 8;
            unsigned wA = cvtpk(sa[kg][rb + 0], sa[kg][rb + 1]);
            unsigned wB = cvtpk(sa[kg][rb + 4], sa[kg][rb + 5]);
            unsigned wC = cvtpk(sa[kg][rb + 2], sa[kg][rb + 3]);
            unsigned wD = cvtpk(sa[kg][rb + 6], sa[kg][rb + 7]);
            iv2 r0 = pl32swap((int)wA, (int)wB);
            iv2 r1 = pl32swap((int)wC, (int)wD);
            union { uint4 u; bf16x8 v; } pu;
            pu.u = make_uint4((unsigned)r0.x, (unsigned)r1.x, (unsigned)r0.y, (unsigned)r1.y);
            const int ks = kg * 2 + ks2;
#pragma unroll
            for (int vg = 0; vg < 2; ++vg) {
              const int vrow = vg * 32 + l31;
              bf16x8 vf = *(const bf16x8*)((const char*)&Vs[c0][0] + vrow * 128 +
                                           (((2 * ks + hi) ^ (vrow & 7)) << 4));
              oacc[vg] = __builtin_amdgcn_mfma_f32_32x32x16_bf16(vf, pu.v, oacc[vg], 0, 0, 0);
            }
          }
        __builtin_amdgcn_s_setprio(0);
      }
      // ---- single wait + barrier: tile kt+1 landed; buf (kt+2)%3 WAR-safe ----
      if (kt + 2 < ntiles)
        asm volatile("s_waitcnt vmcnt(8)" ::: "memory");
      else
        asm volatile("s_waitcnt vmcnt(0)" ::: "memory");
      __builtin_amdgcn_s_barrier();
      int tmp = c0; c0 = c1; c1 = c2; c2 = tmp;
    }
    // ---- epilogue: d = vg*32 + 8j + 4hi + 0..3, packed dwordx2 stores ----
    const float inv = 1.0f / l_;
    unsigned short* Orow = O + ((size_t)(b * SEQ + qrow)) * DM + h * DK;
#pragma unroll
    for (int vg = 0; vg < 2; ++vg)
#pragma unroll
      for (int j = 0; j < 4; ++j) {
        unsigned lo = cvtpk(oacc[vg][4 * j + 0] * inv, oacc[vg][4 * j + 1] * inv);
        unsigned hh = cvtpk(oacc[vg][4 * j + 2] * inv, oacc[vg][4 * j + 3] * inv);
        *(uint2*)&Orow[vg * 32 + 8 * j + 4 * hi] = make_uint2(lo, hh);
      }
  }
#undef STAGE
}

extern "C" void kernel_launch(void* const* d_in, const int* in_sizes, int n_in,
                              void* d_out, int out_size, void* d_ws, size_t ws_size,
                              hipStream_t stream) {
  const float* x = (const float*)d_in[0];
  const int* tp = (const int*)d_in[1];
  const float* W[4] = {(const float*)d_in[2], (const float*)d_in[3],
                       (const float*)d_in[4], (const float*)d_in[5]};
  unsigned short* xb = (unsigned short*)d_ws;              // [8192][1024]
  unsigned short* wb0 = xb + (size_t)8192 * 1024;          // Wq;Wk;Wv;Wo contiguous
  unsigned short* wb3 = wb0 + (size_t)3 * 1024 * 1024;     // Wo
  float2* tab = (float2*)(wb0 + (size_t)4 * 1024 * 1024);  // [2048][32]
  unsigned short* Qb = (unsigned short*)(tab + SEQ * 32);  // [B][H][S][64]
  unsigned short* Kb = Qb + (size_t)8192 * 1024;           // [B][H][S][64]
  unsigned short* VTb = Kb + (size_t)8192 * 1024;          // [B][H][64][S]
  unsigned short* Ob = VTb + (size_t)8192 * 1024;          // [B][S][D]

  k_cvt<<<8192, 256, 0, stream>>>(x, xb, 2097152);
  k_cvtw<<<4096, 256, 0, stream>>>(W[0], W[1], W[2], W[3], wb0);
  k_tab<<<256, 256, 0, stream>>>(tab);
  k_gemm<3><<<dim3(64, 24), 256, 0, stream>>>(xb, wb0, Qb, VTb, tp, tab, 8192, 3072, 1024);
  k_attn<<<1024, 128, 0, stream>>>(Qb, Kb, VTb, Ob);
  k_gemm<1><<<dim3(64, 8), 256, 0, stream>>>(Ob, wb3, d_out, nullptr, nullptr, nullptr,
                                             8192, 1024, 1024);
}

// Round 14
// 178.677 us; speedup vs baseline: 1.1847x; 1.1847x over previous
//
#include <hip/hip_runtime.h>
#include <stdint.h>

#define SEQ 2048
#define NH  16
#define DK  64
#define DM  1024
#define C2SM 0.18033688011112042f   // 0.125 * log2(e): folds 1/sqrt(64) into exp2

typedef __bf16 bf16x8 __attribute__((ext_vector_type(8)));
typedef float  f32x4  __attribute__((ext_vector_type(4)));
typedef float  f32x16 __attribute__((ext_vector_type(16)));
typedef int    iv2    __attribute__((ext_vector_type(2)));
typedef void __attribute__((address_space(3))) lds_void;
typedef const void __attribute__((address_space(1))) glb_void;

__device__ __forceinline__ unsigned short f2b(float f) {
  unsigned int u = __float_as_uint(f);
  u += 0x7fffu + ((u >> 16) & 1u);
  return (unsigned short)(u >> 16);
}
__device__ __forceinline__ float b2f(unsigned short h) {
  return __uint_as_float(((unsigned int)h) << 16);
}
__device__ __forceinline__ void gload_lds16(const void* g, void* lds) {
  __builtin_amdgcn_global_load_lds((glb_void*)(uintptr_t)g,
                                   (lds_void*)(unsigned int)(uintptr_t)lds,
                                   16, 0, 0);
}
// pack two f32 -> one u32 of two bf16 (RNE), single VALU op (no builtin, m240)
__device__ __forceinline__ unsigned int cvtpk(float lo, float hi) {
  unsigned int r;
  asm("v_cvt_pk_bf16_f32 %0, %1, %2" : "=v"(r) : "v"(lo), "v"(hi));
  return r;
}
__device__ __forceinline__ iv2 pl32swap(int a, int b) {
  return __builtin_amdgcn_permlane32_swap(a, b, false, false);
}

// ---------------- f32 -> bf16 convert (x) ----------------
__global__ __launch_bounds__(256) void k_cvt(const float* __restrict__ src,
                                             unsigned short* __restrict__ dst, int n4) {
  int i = blockIdx.x * 256 + threadIdx.x;
  if (i >= n4) return;
  float4 v = ((const float4*)src)[i];
  uint2 o;
  o.x = (unsigned int)f2b(v.x) | ((unsigned int)f2b(v.y) << 16);
  o.y = (unsigned int)f2b(v.z) | ((unsigned int)f2b(v.w) << 16);
  ((uint2*)dst)[i] = o;
}

// ---------------- all 4 weights -> contiguous bf16 ----------------
__global__ __launch_bounds__(256) void k_cvtw(const float* __restrict__ w0,
                                              const float* __restrict__ w1,
                                              const float* __restrict__ w2,
                                              const float* __restrict__ w3,
                                              unsigned short* __restrict__ dst) {
  int i = blockIdx.x * 256 + threadIdx.x;   // 0..2^20-1 (float4 units)
  const float* s = (i < 524288) ? ((i < 262144) ? w0 : w1)
                                : ((i < 786432) ? w2 : w3);
  float4 v = ((const float4*)s)[i & 262143];
  uint2 o;
  o.x = (unsigned int)f2b(v.x) | ((unsigned int)f2b(v.y) << 16);
  o.y = (unsigned int)f2b(v.z) | ((unsigned int)f2b(v.w) << 16);
  ((uint2*)dst)[i] = o;
}

// ---------------- RoPE cos/sin table: [SEQ][32] ----------------
__global__ __launch_bounds__(256) void k_tab(float2* __restrict__ tab) {
  int i = blockIdx.x * 256 + threadIdx.x;
  int p = i >> 5, f = i & 31;
  float freq = powf(10000.0f, -(float)(2 * f) / (float)DK);
  float ang = (float)p * freq;
  tab[i] = make_float2(cosf(ang), sinf(ang));
}

// ---------------- GEMM: C = A[M][K] * B[N][K]^T (bf16 in) ----------------
// R8-proven config: 128x128 tile, depth-2 pipeline (3 LDS buffers), counted
// vmcnt(4), T2 slot swizzle (pre-swizzled source + same XOR on reads).
// MODE 1: f32 out, row-major [M][N]                        (final projection)
// MODE 3: fused QKV. N=3072 (Wq;Wk;Wv). Q/K cols: RoPE applied in-register
//         (pair partner via shfl_xor lane^1), bf16 out to [B][NH][SEQ][DK]
//         (Q at C, K at C+8M). V cols: bf16 out to C2 as V^T [B][NH][DK][SEQ]
//         directly (packed uint2: 4 consecutive s per thread) — R13-verified.
template <int MODE>
__global__ __launch_bounds__(256) void k_gemm(const unsigned short* __restrict__ A,
                                              const unsigned short* __restrict__ B,
                                              void* __restrict__ C, void* __restrict__ C2,
                                              const int* __restrict__ pos,
                                              const float2* __restrict__ tab,
                                              int M, int N, int K) {
  __shared__ __align__(16) unsigned short As[3][4096];
  __shared__ __align__(16) unsigned short Bs[3][4096];
  const int tid = threadIdx.x;
  const int wid = tid >> 6, lane = tid & 63;
  const int lr = lane & 15, lk = lane >> 4;
  const int wr = wid >> 1, wc = wid & 1;
  const int m0 = blockIdx.x * 128, n0 = blockIdx.y * 128;
  const int r0 = tid >> 2;                                  // staging row (rep0)
  const int csw = (((tid & 3) ^ ((r0 >> 1) & 3)) << 3);     // pre-swizzled src col
  const int ss = ((lk ^ ((lr >> 1) & 3)) << 3);             // swizzled read slot
  f32x4 acc[4][4] = {};

#define GSTAGE(bi, k0)                                                       \
  do {                                                                       \
    gload_lds16(A + (size_t)(m0 + r0) * K + (k0) + csw, &As[bi][wid * 512]); \
    gload_lds16(A + (size_t)(m0 + 64 + r0) * K + (k0) + csw,                 \
                &As[bi][2048 + wid * 512]);                                  \
    gload_lds16(B + (size_t)(n0 + r0) * K + (k0) + csw, &Bs[bi][wid * 512]); \
    gload_lds16(B + (size_t)(n0 + 64 + r0) * K + (k0) + csw,                 \
                &Bs[bi][2048 + wid * 512]);                                  \
  } while (0)

  const int nt = K >> 5;
  GSTAGE(0, 0);
  if (nt > 1) {
    GSTAGE(1, 32);
    asm volatile("s_waitcnt vmcnt(4)" ::: "memory");   // buf0 landed, buf1 flying
  } else {
    asm volatile("s_waitcnt vmcnt(0)" ::: "memory");
  }
  __builtin_amdgcn_s_barrier();
  int c0 = 0, c1 = 1, c2 = 2;
  for (int t = 0; t < nt; ++t) {
    if (t + 2 < nt) GSTAGE(c2, (t + 2) * 32);          // overwrites buf read at t-1
    bf16x8 af[4], bfv[4];
#pragma unroll
    for (int i = 0; i < 4; ++i)
      af[i] = *(const bf16x8*)&As[c0][(wr * 64 + i * 16 + lr) * 32 + ss];
#pragma unroll
    for (int j = 0; j < 4; ++j)
      bfv[j] = *(const bf16x8*)&Bs[c0][(wc * 64 + j * 16 + lr) * 32 + ss];
    __builtin_amdgcn_s_setprio(1);
#pragma unroll
    for (int i = 0; i < 4; ++i)
#pragma unroll
      for (int j = 0; j < 4; ++j)
        acc[i][j] = __builtin_amdgcn_mfma_f32_16x16x32_bf16(af[i], bfv[j], acc[i][j], 0, 0, 0);
    __builtin_amdgcn_s_setprio(0);
    if (t + 1 < nt) {
      if (t + 2 < nt)
        asm volatile("s_waitcnt vmcnt(4)" ::: "memory");  // t+1 landed, t+2 flying
      else
        asm volatile("s_waitcnt vmcnt(0)" ::: "memory");
      __builtin_amdgcn_s_barrier();                       // + buf c0 consumed by all
    }
    int tmp = c0; c0 = c1; c1 = c2; c2 = tmp;
  }
#undef GSTAGE

  if (MODE == 1) {
#pragma unroll
    for (int i = 0; i < 4; ++i) {
      const int rbase = m0 + wr * 64 + i * 16 + lk * 4;
#pragma unroll
      for (int j = 0; j < 4; ++j) {
        const int col = n0 + wc * 64 + j * 16 + lr;
#pragma unroll
        for (int r = 0; r < 4; ++r)
          ((float*)C)[(size_t)(rbase + r) * N + col] = acc[i][j][r];
      }
    }
  } else {
    const int tt = n0 >> 10;                  // 0=Q 1=K 2=V, uniform per block
    if (tt == 2) {
      // direct V^T: VT[((bb*NH+h)*DK+d)*SEQ + s], 4 consecutive s -> uint2
#pragma unroll
      for (int i = 0; i < 4; ++i) {
        const int rbase = m0 + wr * 64 + i * 16 + lk * 4;
        const int bb = rbase >> 11;
        const int s0 = rbase & (SEQ - 1);
#pragma unroll
        for (int j = 0; j < 4; ++j) {
          const int col = n0 + wc * 64 + j * 16 + lr;
          const int h = (col >> 6) & 15, d = col & 63;
          uint2 pv;
          pv.x = cvtpk(acc[i][j][0], acc[i][j][1]);
          pv.y = cvtpk(acc[i][j][2], acc[i][j][3]);
          *(uint2*)&((unsigned short*)C2)[(((size_t)bb * NH + h) * DK + d) * SEQ + s0] = pv;
        }
      }
    } else {
#pragma unroll
      for (int i = 0; i < 4; ++i) {
        const int rbase = m0 + wr * 64 + i * 16 + lk * 4;
        const int bb = rbase >> 11;
        int prr[4];
#pragma unroll
        for (int r = 0; r < 4; ++r)
          prr[r] = pos[bb * SEQ + ((rbase + r) & (SEQ - 1))];
#pragma unroll
        for (int j = 0; j < 4; ++j) {
          const int col = n0 + wc * 64 + j * 16 + lr;
          const int h = (col >> 6) & 15, d = col & 63;
          const int f = d >> 1;
#pragma unroll
          for (int r = 0; r < 4; ++r) {
            float v = acc[i][j][r];
            float pv = __shfl_xor(v, 1);
            float2 cs = tab[(size_t)prr[r] * 32 + f];
            float o = (d & 1) ? __builtin_fmaf(pv, cs.y, v * cs.x)
                              : __builtin_fmaf(-pv, cs.y, v * cs.x);
            const int s = (rbase + r) & (SEQ - 1);
            ((unsigned short*)C)[(size_t)tt * 8388608 +
                                 ((((size_t)bb * NH + h) * SEQ) + s) * DK + d] = f2b(o);
          }
        }
      }
    }
  }
}

// ---------------- causal flash attention: single-pass heavy-first, 2048 blocks ----------------
// 2048 blocks x 128 threads (2 waves x 32 q-rows, QBLK=64), one q-tile each.
// qt = 31 - (n>>6): heaviest blocks dispatched FIRST (LPT) — 1280 resident
// (5 blocks/CU, LDS-capped; 31% occupancy cap vs fold's 25%) and 768 queued
// blocks backfill freed slots dynamically. Robust to assignment: relies only
// on slot refill, not on any workgroup->CU mapping. bh = n&63 keeps XCD-local
// K/V (R9-verified). Inner loop byte-identical to the R12-proven 78us kernel:
// double-buffer, 2 barriers + counted vmcnt(8) per tile.
__global__ __launch_bounds__(128) void k_attn(const unsigned short* __restrict__ Q,
                                              const unsigned short* __restrict__ K,
                                              const unsigned short* __restrict__ VT,
                                              unsigned short* __restrict__ O) {
  __shared__ __align__(16) unsigned short Ks[2][64 * 64];
  __shared__ __align__(16) unsigned short Vs[2][64 * 64];
  const int tid = threadIdx.x, wid = tid >> 6, lane = tid & 63;
  const int l31 = lane & 31, hi = lane >> 5;
  const int n = blockIdx.x;
  const int bh = n & 63;                       // bh-major: XCD = bh%8
  const int qt = 31 - (n >> 6);                // heavy-first (LPT)
  const unsigned short* Qp = Q + (size_t)bh * SEQ * DK;
  const unsigned short* Kp = K + (size_t)bh * SEQ * DK;
  const unsigned short* Vp = VT + (size_t)bh * DK * SEQ;   // [64 d][SEQ]
  const int b = bh >> 4, h = bh & (NH - 1);

#define STAGE(bi, kb)                                                          \
  do {                                                                         \
    _Pragma("unroll") for (int i = 0; i < 4; ++i) {                            \
      const int c = i * 128 + tid;                                             \
      const int row = c >> 3, sl = ((c & 7) ^ (row & 7)) << 3;                 \
      gload_lds16(Kp + (size_t)((kb) + row) * DK + sl,                         \
                  &Ks[bi][(i * 128 + wid * 64) * 8]);                          \
      gload_lds16(Vp + (size_t)row * SEQ + (kb) + sl,                          \
                  &Vs[bi][(i * 128 + wid * 64) * 8]);                          \
    }                                                                          \
  } while (0)

  const int qw = qt * 64 + wid * 32;
  const int qrow = qw + l31;
  bf16x8 qf[4];
#pragma unroll
  for (int ks = 0; ks < 4; ++ks)
    qf[ks] = *(const bf16x8*)&Qp[(size_t)qrow * DK + ks * 16 + hi * 8];
  f32x16 oacc[2] = {};
  float m_ = -1e30f, l_ = 0.f;
  const int ntiles = qt + 1;
  STAGE(0, 0);                               // prologue prefetch
  for (int kt = 0; kt < ntiles; ++kt) {
    const int cur = kt & 1;
    const int kb = kt * 64;
    if (kt + 1 < ntiles) {
      STAGE(cur ^ 1, kb + 64);               // issue next tile's 8 loads
      asm volatile("s_waitcnt vmcnt(8)" ::: "memory");   // cur's 8 landed
    } else {
      asm volatile("s_waitcnt vmcnt(0)" ::: "memory");
    }
    __builtin_amdgcn_s_barrier();            // both waves: cur staged
    {
      // ---- QK^T (swapped): sa[kg] regs = kcols kg*32+(r&3)+8(r>>2)+4hi ----
      f32x16 sa[2];
      __builtin_amdgcn_s_setprio(1);
#pragma unroll
      for (int kg = 0; kg < 2; ++kg) {
        const int krow = kg * 32 + l31;
        f32x16 z = {};
#pragma unroll
        for (int ks = 0; ks < 4; ++ks) {
          bf16x8 kf = *(const bf16x8*)((const char*)&Ks[cur][0] + krow * 128 +
                                       (((2 * ks + hi) ^ (krow & 7)) << 4));
          z = __builtin_amdgcn_mfma_f32_32x32x16_bf16(kf, qf[ks], z, 0, 0, 0);
        }
        sa[kg] = z;
      }
      __builtin_amdgcn_s_setprio(0);
      // ---- causal mask (diagonal tile only) ----
      if (kb + 64 > qw) {
        const int th0 = qrow - kb - 4 * hi;
#pragma unroll
        for (int kg = 0; kg < 2; ++kg) {
          const int th = th0 - kg * 32;
#pragma unroll
          for (int r = 0; r < 16; ++r) {
            const int cst = (r & 3) + 8 * (r >> 2);
            if (cst > th) sa[kg][r] = -1e30f;
          }
        }
      }
      // ---- row max: in-register tree + lane-pair swap ----
      float mx;
      {
        float a0 = fmaxf(fmaxf(sa[0][0], sa[0][1]), fmaxf(sa[0][2], sa[0][3]));
        float a1 = fmaxf(fmaxf(sa[0][4], sa[0][5]), fmaxf(sa[0][6], sa[0][7]));
        float a2 = fmaxf(fmaxf(sa[0][8], sa[0][9]), fmaxf(sa[0][10], sa[0][11]));
        float a3 = fmaxf(fmaxf(sa[0][12], sa[0][13]), fmaxf(sa[0][14], sa[0][15]));
        float a4 = fmaxf(fmaxf(sa[1][0], sa[1][1]), fmaxf(sa[1][2], sa[1][3]));
        float a5 = fmaxf(fmaxf(sa[1][4], sa[1][5]), fmaxf(sa[1][6], sa[1][7]));
        float a6 = fmaxf(fmaxf(sa[1][8], sa[1][9]), fmaxf(sa[1][10], sa[1][11]));
        float a7 = fmaxf(fmaxf(sa[1][12], sa[1][13]), fmaxf(sa[1][14], sa[1][15]));
        mx = fmaxf(fmaxf(fmaxf(a0, a1), fmaxf(a2, a3)),
                   fmaxf(fmaxf(a4, a5), fmaxf(a6, a7)));
        iv2 t = pl32swap(__float_as_int(mx), __float_as_int(mx));
        mx = fmaxf(__int_as_float(t.x), __int_as_float(t.y));
      }
      // ---- defer-max: rescale only when running max moved by > 16 (raw) ----
      if (!__all(mx <= m_ + 16.f)) {
        const float mn = fmaxf(m_, mx);
        const float sc = __builtin_amdgcn_exp2f((m_ - mn) * C2SM);
        m_ = mn;
        l_ *= sc;
#pragma unroll
        for (int vg = 0; vg < 2; ++vg)
#pragma unroll
          for (int r = 0; r < 16; ++r) oacc[vg][r] *= sc;
      }
      // ---- exp + row sum ----
      const float mc = m_ * C2SM;
      float sum = 0.f;
#pragma unroll
      for (int kg = 0; kg < 2; ++kg)
#pragma unroll
        for (int r = 0; r < 16; ++r) {
          const float p = __builtin_amdgcn_exp2f(__builtin_fmaf(sa[kg][r], C2SM, -mc));
          sa[kg][r] = p;
          sum += p;
        }
      {
        iv2 t = pl32swap(__float_as_int(sum), __float_as_int(sum));
        l_ += __int_as_float(t.x) + __int_as_float(t.y);
      }
      // ---- PV: P->bf16 A-frag via cvt_pk + permlane32_swap, mfma(V^T, P) ----
      __builtin_amdgcn_s_setprio(1);
#pragma unroll
      for (int kg = 0; kg < 2; ++kg)
#pragma unroll
        for (int ks2 = 0; ks2 < 2; ++ks2) {
          const int rb = ks2 * 8;
          unsigned wA = cvtpk(sa[kg][rb + 0], sa[kg][rb + 1]);
          unsigned wB = cvtpk(sa[kg][rb + 4], sa[kg][rb + 5]);
          unsigned wC = cvtpk(sa[kg][rb + 2], sa[kg][rb + 3]);
          unsigned wD = cvtpk(sa[kg][rb + 6], sa[kg][rb + 7]);
          iv2 r0 = pl32swap((int)wA, (int)wB);
          iv2 r1 = pl32swap((int)wC, (int)wD);
          union { uint4 u; bf16x8 v; } pu;
          pu.u = make_uint4((unsigned)r0.x, (unsigned)r1.x, (unsigned)r0.y, (unsigned)r1.y);
          const int ks = kg * 2 + ks2;
#pragma unroll
          for (int vg = 0; vg < 2; ++vg) {
            const int vrow = vg * 32 + l31;
            bf16x8 vf = *(const bf16x8*)((const char*)&Vs[cur][0] + vrow * 128 +
                                         (((2 * ks + hi) ^ (vrow & 7)) << 4));
            oacc[vg] = __builtin_amdgcn_mfma_f32_32x32x16_bf16(vf, pu.v, oacc[vg], 0, 0, 0);
          }
        }
      __builtin_amdgcn_s_setprio(0);
    }
    __builtin_amdgcn_s_barrier();            // cur consumed by both waves
  }
  // ---- epilogue: d = vg*32 + 8j + 4hi + 0..3, packed dwordx2 stores ----
  const float inv = 1.0f / l_;
  unsigned short* Orow = O + ((size_t)(b * SEQ + qrow)) * DM + h * DK;
#pragma unroll
  for (int vg = 0; vg < 2; ++vg)
#pragma unroll
    for (int j = 0; j < 4; ++j) {
      unsigned lo = cvtpk(oacc[vg][4 * j + 0] * inv, oacc[vg][4 * j + 1] * inv);
      unsigned hh = cvtpk(oacc[vg][4 * j + 2] * inv, oacc[vg][4 * j + 3] * inv);
      *(uint2*)&Orow[vg * 32 + 8 * j + 4 * hi] = make_uint2(lo, hh);
    }
#undef STAGE
}

extern "C" void kernel_launch(void* const* d_in, const int* in_sizes, int n_in,
                              void* d_out, int out_size, void* d_ws, size_t ws_size,
                              hipStream_t stream) {
  const float* x = (const float*)d_in[0];
  const int* tp = (const int*)d_in[1];
  const float* W[4] = {(const float*)d_in[2], (const float*)d_in[3],
                       (const float*)d_in[4], (const float*)d_in[5]};
  unsigned short* xb = (unsigned short*)d_ws;              // [8192][1024]
  unsigned short* wb0 = xb + (size_t)8192 * 1024;          // Wq;Wk;Wv;Wo contiguous
  unsigned short* wb3 = wb0 + (size_t)3 * 1024 * 1024;     // Wo
  float2* tab = (float2*)(wb0 + (size_t)4 * 1024 * 1024);  // [2048][32]
  unsigned short* Qb = (unsigned short*)(tab + SEQ * 32);  // [B][H][S][64]
  unsigned short* Kb = Qb + (size_t)8192 * 1024;           // [B][H][S][64]
  unsigned short* VTb = Kb + (size_t)8192 * 1024;          // [B][H][64][S]
  unsigned short* Ob = VTb + (size_t)8192 * 1024;          // [B][S][D]

  k_cvt<<<8192, 256, 0, stream>>>(x, xb, 2097152);
  k_cvtw<<<4096, 256, 0, stream>>>(W[0], W[1], W[2], W[3], wb0);
  k_tab<<<256, 256, 0, stream>>>(tab);
  k_gemm<3><<<dim3(64, 24), 256, 0, stream>>>(xb, wb0, Qb, VTb, tp, tab, 8192, 3072, 1024);
  k_attn<<<2048, 128, 0, stream>>>(Qb, Kb, VTb, Ob);
  k_gemm<1><<<dim3(64, 8), 256, 0, stream>>>(Ob, wb3, d_out, nullptr, nullptr, nullptr,
                                             8192, 1024, 1024);
}